// Round 2
// baseline (1262.425 us; speedup 1.0000x reference)
//
#include <hip/hip_runtime.h>
#include <stdint.h>

#define HID 256
#define BATCH 16384
#define SEQ 20
#define OUTF 214
#define BM 64
#define NBLK (BATCH/BM)   // 256 blocks, one per CU
#define ROWE 264          // h row stride in bf16 elems (2-way-max LDS bank aliasing)
#define OLD 228           // out_lds row stride in floats (228%32=4 -> 2-way max on b128)

typedef __attribute__((ext_vector_type(8))) short short8;
typedef __attribute__((ext_vector_type(4))) float f32x4;

#define MFMA(a,b,c) __builtin_amdgcn_mfma_f32_16x16x32_bf16((a),(b),(c),0,0,0)
// soft barrier: order LDS only; let global loads/stores drain across the barrier
#define SBAR() asm volatile("s_waitcnt lgkmcnt(0)\n\ts_barrier" ::: "memory")

__device__ __forceinline__ unsigned short f2bf(float f) {
    unsigned int u = __builtin_bit_cast(unsigned int, f);
    u += 0x7FFFu + ((u >> 16) & 1u);   // RNE
    return (unsigned short)(u >> 16);
}
__device__ __forceinline__ float sigm(float x)     { return __fdividef(1.0f, 1.0f + __expf(-x)); }
__device__ __forceinline__ float tanhfast(float x) { return 1.0f - __fdividef(2.0f, __expf(2.0f*x) + 1.0f); }

// ---------------- prep: pack weights into MFMA fragment-linear layout ----------------
// frag layout for a [Ntiles][Ktiles] matrix of 16x32 tiles: element (n,k) lives at
// short index (((n>>4)*KT + (k>>5))*64 + ((n&15) | (((k>>3)&3)<<4)))*8 + (k&7)
__global__ __launch_bounds__(256) void prep_kernel(
    const float* __restrict__ W_proj, const float* __restrict__ W_ih,
    const float* __restrict__ W_hh,  const float* __restrict__ b_ih,
    const float* __restrict__ b_hh,  const float* __restrict__ W_tech,
    const float* __restrict__ b_tech, const float* __restrict__ W_phase,
    const float* __restrict__ b_phase, const float* __restrict__ W_time,
    const float* __restrict__ b_time,
    unsigned short* __restrict__ Wc, unsigned short* __restrict__ Wi,
    unsigned short* __restrict__ Wo, unsigned short* __restrict__ Wp,
    float* __restrict__ b_comb, float* __restrict__ b_out)
{
    const int n = blockIdx.x;    // 0..1023 (gate row)
    const int k = threadIdx.x;   // 0..255
    const int lane = (n & 15) | (((k >> 3) & 3) << 4);
    const int e  = k & 7;
    const int tn = n >> 4;
    {
        float wi = W_ih[n*HID + k], wh = W_hh[n*HID + k];
        int idx = ((tn*8 + (k>>5))*64 + lane)*8 + e;
        Wi[idx] = f2bf(wi);
        Wc[idx] = f2bf(wi + wh);
    }
    if (n < 224) {   // out projection: [tech(200) | phase(13) | time(1) | zero-pad]
        float v = 0.0f;
        if (n < 200)       v = W_tech[n*HID + k];
        else if (n < 213)  v = W_phase[(n-200)*HID + k];
        else if (n == 213) v = W_time[k];
        int idx = ((tn*8 + (k>>5))*64 + lane)*8 + e;
        Wo[idx] = f2bf(v);
    }
    if (n < 256 && k < 128) {  // W_proj padded K 100->128
        float v = (k < 100) ? W_proj[n*100 + k] : 0.0f;
        int idx = ((tn*4 + (k>>5))*64 + lane)*8 + e;
        Wp[idx] = f2bf(v);
    }
    if (n < 4) b_comb[n*256 + k] = b_ih[n*256 + k] + b_hh[n*256 + k];
    if (n == 4 && k < 224) {
        float v = 0.0f;
        if (k < 200)       v = b_tech[k];
        else if (k < 213)  v = b_phase[k-200];
        else if (k == 213) v = b_time[0];
        b_out[k] = v;
    }
}

// ---------------- main persistent LSTM kernel ----------------
// 256 blocks x 512 threads (8 waves), one block per CU, 64 batch rows per block.
// Per step: [E: elementwise h_t -> hbuf + coalesced copy of out(t-1)] SBAR
//           [O: out-proj(t) -> out_lds; G: gates(t+1) -> accG]        SBAR
__global__ __launch_bounds__(512, 2) void lstm_kernel(
    const float* __restrict__ noise, const float* __restrict__ b_proj,
    const unsigned short* __restrict__ Wc, const unsigned short* __restrict__ Wi,
    const unsigned short* __restrict__ Wo_g, const unsigned short* __restrict__ Wp,
    const float* __restrict__ b_comb, const float* __restrict__ b_out,
    float* __restrict__ out)
{
    __shared__ __attribute__((aligned(16))) unsigned short hbuf[BM * ROWE];  // 33.0 KiB
    __shared__ __attribute__((aligned(16))) float out_lds[BM * OLD];         // 57.0 KiB

    const int tid  = threadIdx.x;
    const int w    = tid >> 6;
    const int lane = tid & 63;
    const int lr   = lane & 15;    // D col (= batch m within tile)
    const int lq   = lane >> 4;    // k-slot group; D row group
    const int blk  = blockIdx.x;

    { // stage noise -> hbuf as bf16 (cols 0..99), zero-pad 100..127
        const float* nsrc = noise + (size_t)blk * BM * 100;
        for (int i = tid; i < BM*100; i += 512) {
            int m = i / 100; int kk = i - m*100;
            hbuf[m*ROWE + kk] = f2bf(nsrc[i]);
        }
        for (int i = tid; i < BM*28; i += 512) {
            int m = i / 28; int kk = i - m*28;
            hbuf[m*ROWE + 100 + kk] = 0;
        }
    }

    const int jb0 = w*32;
    f32x4 bi[2][4];
    #pragma unroll
    for (int jt = 0; jt < 2; ++jt)
        #pragma unroll
        for (int g = 0; g < 4; ++g)
            bi[jt][g] = *(const f32x4*)&b_comb[g*256 + jb0 + jt*16 + lq*4];
    f32x4 bp[2];
    #pragma unroll
    for (int jt = 0; jt < 2; ++jt)
        bp[jt] = *(const f32x4*)&b_proj[jb0 + jt*16 + lq*4];
    f32x4 bo0 = *(const f32x4*)&b_out[w*16 + lq*4];
    f32x4 bo1 = {0.f,0.f,0.f,0.f};
    if (w < 6) bo1 = *(const f32x4*)&b_out[(8+w)*16 + lq*4];

    f32x4 c_[2][4];
    #pragma unroll
    for (int jt = 0; jt < 2; ++jt)
        #pragma unroll
        for (int mt = 0; mt < 4; ++mt) c_[jt][mt] = f32x4{0.f,0.f,0.f,0.f};

    SBAR();

    // ---- x0 = noise @ W_proj.T + b_proj  (K padded to 128) -> hbuf
    {
        f32x4 acc[2][4];
        #pragma unroll
        for (int jt = 0; jt < 2; ++jt)
            #pragma unroll
            for (int mt = 0; mt < 4; ++mt) acc[jt][mt] = f32x4{0.f,0.f,0.f,0.f};
        #pragma unroll
        for (int kk = 0; kk < 4; ++kk) {
            short8 b[4];
            #pragma unroll
            for (int mt = 0; mt < 4; ++mt)
                b[mt] = *(const short8*)&hbuf[(mt*16+lr)*ROWE + kk*32 + lq*8];
            #pragma unroll
            for (int jt = 0; jt < 2; ++jt) {
                short8 a = *(const short8*)&Wp[(((w*2+jt)*4 + kk)*64 + lane)*8];
                #pragma unroll
                for (int mt = 0; mt < 4; ++mt)
                    acc[jt][mt] = MFMA(a, b[mt], acc[jt][mt]);
            }
        }
        SBAR();  // all reads of noise staging done
        #pragma unroll
        for (int jt = 0; jt < 2; ++jt) {
            const int jb = jb0 + jt*16 + lq*4;
            #pragma unroll
            for (int mt = 0; mt < 4; ++mt) {
                f32x4 v = acc[jt][mt] + bp[jt];
                unsigned int p0 = (unsigned int)f2bf(v.x) | ((unsigned int)f2bf(v.y) << 16);
                unsigned int p1 = (unsigned int)f2bf(v.z) | ((unsigned int)f2bf(v.w) << 16);
                uint2 pk; pk.x = p0; pk.y = p1;
                *(uint2*)&hbuf[(mt*16+lr)*ROWE + jb] = pk;
            }
        }
    }
    SBAR();

    f32x4 accG[2][4][4];   // gate accumulators, live across E phase

    // gates helper: accG = hbuf @ Wf.T fragments
    auto gates = [&](const unsigned short* __restrict__ Wf) {
        #pragma unroll
        for (int jt = 0; jt < 2; ++jt)
            #pragma unroll
            for (int g = 0; g < 4; ++g)
                #pragma unroll
                for (int mt = 0; mt < 4; ++mt) accG[jt][g][mt] = f32x4{0.f,0.f,0.f,0.f};
        #pragma unroll
        for (int kk = 0; kk < 8; ++kk) {
            short8 b[4];
            #pragma unroll
            for (int mt = 0; mt < 4; ++mt)
                b[mt] = *(const short8*)&hbuf[(mt*16+lr)*ROWE + kk*32 + lq*8];
            #pragma unroll
            for (int jt = 0; jt < 2; ++jt) {
                #pragma unroll
                for (int g = 0; g < 4; ++g) {
                    short8 a = *(const short8*)&Wf[(((g*16 + w*2 + jt)*8 + kk)*64 + lane)*8];
                    #pragma unroll
                    for (int mt = 0; mt < 4; ++mt)
                        accG[jt][g][mt] = MFMA(a, b[mt], accG[jt][g][mt]);
                }
            }
        }
    };

    // coalesced copy of out_lds -> global for step t
    auto copy_out = [&](int t) {
        float* outt = out + (size_t)t * BATCH * OUTF + (size_t)blk * BM * OUTF;
        #pragma unroll
        for (int it = 0; it < 14; ++it) {
            int i = tid + it*512;
            if (it == 13 && i >= 64*107) break;    // 6848 float2 total
            int row = i / 107; int c2 = i - row*107;
            float2 v = *(const float2*)&out_lds[row*OLD + c2*2];
            if (c2 == 106 && v.y < 0.f) v.y = 0.f;   // ReLU on timing col 213
            *(float2*)&outt[(size_t)row*OUTF + c2*2] = v;
        }
    };

    gates(Wi);   // gates(0) from x0 (h0 = 0 -> W_ih only)
    SBAR();

    for (int t = 0; t < SEQ; ++t) {
        // ---- E phase: copy out(t-1) (stores drain across barriers), elementwise -> h_t
        if (t > 0) copy_out(t-1);
        #pragma unroll
        for (int jt = 0; jt < 2; ++jt) {
            const int jb = jb0 + jt*16 + lq*4;
            #pragma unroll
            for (int mt = 0; mt < 4; ++mt) {
                f32x4 xi = accG[jt][0][mt] + bi[jt][0];
                f32x4 xf = accG[jt][1][mt] + bi[jt][1];
                f32x4 xg = accG[jt][2][mt] + bi[jt][2];
                f32x4 xo = accG[jt][3][mt] + bi[jt][3];
                f32x4 cc = c_[jt][mt];
                float hh[4];
                #pragma unroll
                for (int r = 0; r < 4; ++r) {
                    float iv = sigm(xi[r]);
                    float fv = sigm(xf[r]);
                    float gv = tanhfast(xg[r]);
                    float ov = sigm(xo[r]);
                    float cn = fv*cc[r] + iv*gv;
                    cc[r] = cn;
                    hh[r] = ov * tanhfast(cn);
                }
                c_[jt][mt] = cc;
                unsigned int p0 = (unsigned int)f2bf(hh[0]) | ((unsigned int)f2bf(hh[1]) << 16);
                unsigned int p1 = (unsigned int)f2bf(hh[2]) | ((unsigned int)f2bf(hh[3]) << 16);
                uint2 pk; pk.x = p0; pk.y = p1;
                *(uint2*)&hbuf[(mt*16+lr)*ROWE + jb] = pk;
            }
        }
        SBAR();   // h_t visible; out_lds(t-1) fully read

        // ---- O phase: out-proj(t) = h_t @ W_out.T + b_out -> out_lds
        {
            f32x4 oa0[4], oa1[4];
            #pragma unroll
            for (int mt = 0; mt < 4; ++mt) { oa0[mt] = f32x4{0.f,0.f,0.f,0.f}; oa1[mt] = f32x4{0.f,0.f,0.f,0.f}; }
            #pragma unroll
            for (int kk = 0; kk < 8; ++kk) {
                short8 b[4];
                #pragma unroll
                for (int mt = 0; mt < 4; ++mt)
                    b[mt] = *(const short8*)&hbuf[(mt*16+lr)*ROWE + kk*32 + lq*8];
                short8 a0 = *(const short8*)&Wo_g[((w*8 + kk)*64 + lane)*8];
                #pragma unroll
                for (int mt = 0; mt < 4; ++mt) oa0[mt] = MFMA(a0, b[mt], oa0[mt]);
                if (w < 6) {
                    short8 a1 = *(const short8*)&Wo_g[(((8+w)*8 + kk)*64 + lane)*8];
                    #pragma unroll
                    for (int mt = 0; mt < 4; ++mt) oa1[mt] = MFMA(a1, b[mt], oa1[mt]);
                }
            }
            const int col0 = w*16 + lq*4;
            #pragma unroll
            for (int mt = 0; mt < 4; ++mt) {
                f32x4 v = oa0[mt] + bo0;
                *(f32x4*)&out_lds[(mt*16+lr)*OLD + col0] = v;
            }
            if (w < 6) {
                const int col1 = (8+w)*16 + lq*4;
                #pragma unroll
                for (int mt = 0; mt < 4; ++mt) {
                    f32x4 v = oa1[mt] + bo1;
                    *(f32x4*)&out_lds[(mt*16+lr)*OLD + col1] = v;
                }
            }
        }
        // ---- G phase: gates(t+1) from h_t
        if (t < SEQ-1) gates(Wc);
        SBAR();   // out_lds(t) complete; hbuf reads done -> E may overwrite h
    }
    copy_out(SEQ-1);
}

extern "C" void kernel_launch(void* const* d_in, const int* in_sizes, int n_in,
                              void* d_out, int out_size, void* d_ws, size_t ws_size,
                              hipStream_t stream) {
    const float* noise   = (const float*)d_in[0];
    const float* W_proj  = (const float*)d_in[1];
    const float* b_proj  = (const float*)d_in[2];
    const float* W_ih    = (const float*)d_in[3];
    const float* W_hh    = (const float*)d_in[4];
    const float* b_ih    = (const float*)d_in[5];
    const float* b_hh    = (const float*)d_in[6];
    const float* W_tech  = (const float*)d_in[7];
    const float* b_tech  = (const float*)d_in[8];
    const float* W_phase = (const float*)d_in[9];
    const float* b_phase = (const float*)d_in[10];
    const float* W_time  = (const float*)d_in[11];
    const float* b_time  = (const float*)d_in[12];

    char* ws = (char*)d_ws;
    unsigned short* Wc = (unsigned short*)(ws);            // 512 KiB: frag(W_ih + W_hh)
    unsigned short* Wi = (unsigned short*)(ws + 524288);   // 512 KiB: frag(W_ih)
    unsigned short* Wo = (unsigned short*)(ws + 1048576);  // 112 KiB: frag(W_out padded to 224)
    unsigned short* Wp = (unsigned short*)(ws + 1163264);  //  64 KiB: frag(W_proj padded K=128)
    float* b_comb = (float*)(ws + 1228800);                //   4 KiB
    float* b_out  = (float*)(ws + 1232896);                // 896 B

    prep_kernel<<<1024, 256, 0, stream>>>(W_proj, W_ih, W_hh, b_ih, b_hh,
                                          W_tech, b_tech, W_phase, b_phase, W_time, b_time,
                                          Wc, Wi, Wo, Wp, b_comb, b_out);
    lstm_kernel<<<NBLK, 512, 0, stream>>>(noise, b_proj, Wc, Wi, Wo, Wp, b_comb, b_out,
                                          (float*)d_out);
}

// Round 4
// 470.338 us; speedup vs baseline: 2.6841x; 2.6841x over previous
//
#include <hip/hip_runtime.h>
#include <stdint.h>

#define HID 256
#define BATCH 16384
#define SEQ 20
#define OUTF 214
#define BM 64
#define NBLK (BATCH/BM)   // 256 blocks, one per CU
#define ROWE 264          // h row stride in bf16 elems (16B-aligned rows, conflict-free b128 reads)

typedef __attribute__((ext_vector_type(8))) short short8;
typedef __attribute__((ext_vector_type(4))) float f32x4;

#define MFMA(a,b,c) __builtin_amdgcn_mfma_f32_16x16x32_bf16((a),(b),(c),0,0,0)
// soft barrier: order LDS only; global loads/stores drain across the barrier
#define SBAR() asm volatile("s_waitcnt lgkmcnt(0)\n\ts_barrier" ::: "memory")

__device__ __forceinline__ unsigned short f2bf(float f) {
    unsigned int u = __builtin_bit_cast(unsigned int, f);
    u += 0x7FFFu + ((u >> 16) & 1u);   // RNE
    return (unsigned short)(u >> 16);
}
__device__ __forceinline__ float sigm(float x)     { return __fdividef(1.0f, 1.0f + __expf(-x)); }
__device__ __forceinline__ float tanhfast(float x) { return 1.0f - __fdividef(2.0f, __expf(2.0f*x) + 1.0f); }

// ---------------- prep: pack weights into MFMA fragment-linear layout ----------------
// frag layout for a [Ntiles][Ktiles] matrix of 16x32 tiles: element (n,k) lives at
// short index (((n>>4)*KT + (k>>5))*64 + ((n&15) | (((k>>3)&3)<<4)))*8 + (k&7)
__global__ __launch_bounds__(256) void prep_kernel(
    const float* __restrict__ W_proj, const float* __restrict__ W_ih,
    const float* __restrict__ W_hh,  const float* __restrict__ b_ih,
    const float* __restrict__ b_hh,  const float* __restrict__ W_tech,
    const float* __restrict__ b_tech, const float* __restrict__ W_phase,
    const float* __restrict__ b_phase, const float* __restrict__ W_time,
    const float* __restrict__ b_time,
    unsigned short* __restrict__ Wc, unsigned short* __restrict__ Wi,
    unsigned short* __restrict__ Wo, unsigned short* __restrict__ Wp,
    float* __restrict__ b_comb, float* __restrict__ b_out)
{
    const int n = blockIdx.x;    // 0..1023 (gate row)
    const int k = threadIdx.x;   // 0..255
    const int lane = (n & 15) | (((k >> 3) & 3) << 4);
    const int e  = k & 7;
    const int tn = n >> 4;
    {
        float wi = W_ih[n*HID + k], wh = W_hh[n*HID + k];
        int idx = ((tn*8 + (k>>5))*64 + lane)*8 + e;
        Wi[idx] = f2bf(wi);
        Wc[idx] = f2bf(wi + wh);
    }
    if (n < 224) {   // out projection: [tech(200) | phase(13) | time(1) | zero-pad]
        float v = 0.0f;
        if (n < 200)       v = W_tech[n*HID + k];
        else if (n < 213)  v = W_phase[(n-200)*HID + k];
        else if (n == 213) v = W_time[k];
        int idx = ((tn*8 + (k>>5))*64 + lane)*8 + e;
        Wo[idx] = f2bf(v);
    }
    if (n < 256 && k < 128) {  // W_proj padded K 100->128
        float v = (k < 100) ? W_proj[n*100 + k] : 0.0f;
        int idx = ((tn*4 + (k>>5))*64 + lane)*8 + e;
        Wp[idx] = f2bf(v);
    }
    if (n < 4) b_comb[n*256 + k] = b_ih[n*256 + k] + b_hh[n*256 + k];
    if (n == 4 && k < 224) {
        float v = 0.0f;
        if (k < 200)       v = b_tech[k];
        else if (k < 213)  v = b_phase[k-200];
        else if (k == 213) v = b_time[0];
        b_out[k] = v;
    }
}

// ---------------- main persistent LSTM kernel ----------------
// 256 blocks x 512 threads (8 waves), one block per CU, 64 batch rows per block.
// Double-buffered h in LDS; gates+elementwise in 2 half-passes (acc = 64 f32/lane,
// peak live regs ~175 < 256 -> no scratch spill). 2 soft barriers per step.
// Iter t: [copy_out(t-1) | gepass x2: h_new -> hbuf[p^1]] SBAR
//         [oproj reads h_new (hbuf[p^1]) -> out_lds]      SBAR
__global__ __launch_bounds__(512, 2) void lstm_kernel(
    const float* __restrict__ noise, const float* __restrict__ b_proj,
    const unsigned short* __restrict__ Wc, const unsigned short* __restrict__ Wi,
    const unsigned short* __restrict__ Wo_g, const unsigned short* __restrict__ Wp,
    const float* __restrict__ b_comb, const float* __restrict__ b_out,
    float* __restrict__ out)
{
    __shared__ __attribute__((aligned(16))) unsigned short hbuf[2][BM * ROWE]; // 2 x 33.0 KiB
    __shared__ __attribute__((aligned(16))) float out_lds[BM * OUTF];          // 53.5 KiB

    const int tid  = threadIdx.x;
    const int w    = tid >> 6;
    const int lane = tid & 63;
    const int lr   = lane & 15;    // D col (= batch m within tile)
    const int lq   = lane >> 4;    // k-slot group; D row group
    const int blk  = blockIdx.x;

    { // stage noise -> hbuf[1] as bf16 (cols 0..99), zero-pad 100..127
        const float* nsrc = noise + (size_t)blk * BM * 100;
        for (int i = tid; i < BM*100; i += 512) {
            int m = i / 100; int kk = i - m*100;
            hbuf[1][m*ROWE + kk] = f2bf(nsrc[i]);
        }
        for (int i = tid; i < BM*28; i += 512) {
            int m = i / 28; int kk = i - m*28;
            hbuf[1][m*ROWE + 100 + kk] = 0;
        }
    }

    // biases (16B-aligned vector loads)
    f32x4 bi[2][4];   // [half][gate] for j = P*128 + w*16 + lq*4
    #pragma unroll
    for (int P = 0; P < 2; ++P)
        #pragma unroll
        for (int g = 0; g < 4; ++g)
            bi[P][g] = *(const f32x4*)&b_comb[g*256 + P*128 + w*16 + lq*4];
    f32x4 bo0 = *(const f32x4*)&b_out[w*16 + lq*4];
    f32x4 bo1 = {0.f,0.f,0.f,0.f};
    if (w < 6) bo1 = *(const f32x4*)&b_out[(8+w)*16 + lq*4];

    f32x4 c_[2][4];   // cell state per half
    #pragma unroll
    for (int P = 0; P < 2; ++P)
        #pragma unroll
        for (int mt = 0; mt < 4; ++mt) c_[P][mt] = f32x4{0.f,0.f,0.f,0.f};

    SBAR();   // noise staged

    // ---- x0 = noise @ W_proj.T + b_proj  (reads hbuf[1], writes hbuf[0])
    {
        f32x4 bp[2];
        #pragma unroll
        for (int jt = 0; jt < 2; ++jt)
            bp[jt] = *(const f32x4*)&b_proj[w*32 + jt*16 + lq*4];
        f32x4 acc[2][4];
        #pragma unroll
        for (int jt = 0; jt < 2; ++jt)
            #pragma unroll
            for (int mt = 0; mt < 4; ++mt) acc[jt][mt] = f32x4{0.f,0.f,0.f,0.f};
        #pragma unroll
        for (int kk = 0; kk < 4; ++kk) {
            short8 b[4];
            #pragma unroll
            for (int mt = 0; mt < 4; ++mt)
                b[mt] = *(const short8*)&hbuf[1][(mt*16+lr)*ROWE + kk*32 + lq*8];
            #pragma unroll
            for (int jt = 0; jt < 2; ++jt) {
                short8 a = *(const short8*)&Wp[(((w*2+jt)*4 + kk)*64 + lane)*8];
                #pragma unroll
                for (int mt = 0; mt < 4; ++mt)
                    acc[jt][mt] = MFMA(a, b[mt], acc[jt][mt]);
            }
        }
        #pragma unroll
        for (int jt = 0; jt < 2; ++jt) {
            const int jb = w*32 + jt*16 + lq*4;
            #pragma unroll
            for (int mt = 0; mt < 4; ++mt) {
                f32x4 v = acc[jt][mt] + bp[jt];
                unsigned int p0 = (unsigned int)f2bf(v.x) | ((unsigned int)f2bf(v.y) << 16);
                unsigned int p1 = (unsigned int)f2bf(v.z) | ((unsigned int)f2bf(v.w) << 16);
                uint2 pk; pk.x = p0; pk.y = p1;
                *(uint2*)&hbuf[0][(mt*16+lr)*ROWE + jb] = pk;
            }
        }
    }
    SBAR();   // x0 visible

    // gates+elementwise half-pass: acc 64 f32/lane, dies within the pass
    auto gepass = [&](int P, const unsigned short* __restrict__ Wf, int pc) {
        f32x4 acc[4][4];
        #pragma unroll
        for (int g = 0; g < 4; ++g)
            #pragma unroll
            for (int mt = 0; mt < 4; ++mt) acc[g][mt] = f32x4{0.f,0.f,0.f,0.f};
        #pragma unroll
        for (int kk = 0; kk < 8; ++kk) {
            short8 b[4];
            #pragma unroll
            for (int mt = 0; mt < 4; ++mt)
                b[mt] = *(const short8*)&hbuf[pc][(mt*16+lr)*ROWE + kk*32 + lq*8];
            #pragma unroll
            for (int g = 0; g < 4; ++g) {
                short8 a = *(const short8*)&Wf[(((g*16 + P*8 + w)*8 + kk)*64 + lane)*8];
                #pragma unroll
                for (int mt = 0; mt < 4; ++mt)
                    acc[g][mt] = MFMA(a, b[mt], acc[g][mt]);
            }
        }
        const int jb = P*128 + w*16 + lq*4;
        #pragma unroll
        for (int mt = 0; mt < 4; ++mt) {
            f32x4 xi = acc[0][mt] + bi[P][0];
            f32x4 xf = acc[1][mt] + bi[P][1];
            f32x4 xg = acc[2][mt] + bi[P][2];
            f32x4 xo = acc[3][mt] + bi[P][3];
            f32x4 cc = c_[P][mt];
            float hh[4];
            #pragma unroll
            for (int r = 0; r < 4; ++r) {
                float iv = sigm(xi[r]);
                float fv = sigm(xf[r]);
                float gv = tanhfast(xg[r]);
                float ov = sigm(xo[r]);
                float cn = fv*cc[r] + iv*gv;
                cc[r] = cn;
                hh[r] = ov * tanhfast(cn);
            }
            c_[P][mt] = cc;
            unsigned int p0 = (unsigned int)f2bf(hh[0]) | ((unsigned int)f2bf(hh[1]) << 16);
            unsigned int p1 = (unsigned int)f2bf(hh[2]) | ((unsigned int)f2bf(hh[3]) << 16);
            uint2 pk; pk.x = p0; pk.y = p1;
            *(uint2*)&hbuf[pc^1][(mt*16+lr)*ROWE + jb] = pk;
        }
    };

    // out-proj: h_new (hbuf[pc]) @ W_out.T + b_out -> out_lds (stride OUTF=214)
    auto oproj = [&](int pc) {
        f32x4 oa0[4], oa1[4];
        #pragma unroll
        for (int mt = 0; mt < 4; ++mt) { oa0[mt] = f32x4{0.f,0.f,0.f,0.f}; oa1[mt] = f32x4{0.f,0.f,0.f,0.f}; }
        #pragma unroll
        for (int kk = 0; kk < 8; ++kk) {
            short8 b[4];
            #pragma unroll
            for (int mt = 0; mt < 4; ++mt)
                b[mt] = *(const short8*)&hbuf[pc][(mt*16+lr)*ROWE + kk*32 + lq*8];
            short8 a0 = *(const short8*)&Wo_g[((w*8 + kk)*64 + lane)*8];
            #pragma unroll
            for (int mt = 0; mt < 4; ++mt) oa0[mt] = MFMA(a0, b[mt], oa0[mt]);
            if (w < 6) {
                short8 a1 = *(const short8*)&Wo_g[(((8+w)*8 + kk)*64 + lane)*8];
                #pragma unroll
                for (int mt = 0; mt < 4; ++mt) oa1[mt] = MFMA(a1, b[mt], oa1[mt]);
            }
        }
        const int col0 = w*16 + lq*4;
        #pragma unroll
        for (int mt = 0; mt < 4; ++mt) {
            int row = mt*16 + lr;
            f32x4 v = oa0[mt] + bo0;
            float2 lo; lo.x = v.x; lo.y = v.y;
            float2 hi; hi.x = v.z; hi.y = v.w;
            *(float2*)&out_lds[row*OUTF + col0]     = lo;   // rows are 856B -> 8B-aligned stores
            *(float2*)&out_lds[row*OUTF + col0 + 2] = hi;
        }
        if (w < 5) {
            const int col1 = 128 + w*16 + lq*4;
            #pragma unroll
            for (int mt = 0; mt < 4; ++mt) {
                int row = mt*16 + lr;
                f32x4 v = oa1[mt] + bo1;
                float2 lo; lo.x = v.x; lo.y = v.y;
                float2 hi; hi.x = v.z; hi.y = v.w;
                *(float2*)&out_lds[row*OUTF + col1]     = lo;
                *(float2*)&out_lds[row*OUTF + col1 + 2] = hi;
            }
        } else if (w == 5) {   // tile 13: cols 208..223, valid 208..213, ReLU on 213
            const int col1 = 208 + lq*4;
            #pragma unroll
            for (int mt = 0; mt < 4; ++mt) {
                int row = mt*16 + lr;
                f32x4 v = oa1[mt] + bo1;
                if (lq == 0) {
                    float2 lo; lo.x = v.x; lo.y = v.y;
                    float2 hi; hi.x = v.z; hi.y = v.w;
                    *(float2*)&out_lds[row*OUTF + col1]     = lo;
                    *(float2*)&out_lds[row*OUTF + col1 + 2] = hi;
                } else if (lq == 1) {
                    float2 lo; lo.x = v.x; lo.y = (v.y > 0.f) ? v.y : 0.f;  // col 213 = timing
                    *(float2*)&out_lds[row*OUTF + col1] = lo;
                }
            }
        }
    };

    // flat, fully-coalesced, non-temporal copy out_lds -> out (no L2 pollution)
    auto copy_out = [&](int t) {
        f32x4* dst = (f32x4*)(out + (size_t)t * BATCH * OUTF + (size_t)blk * BM * OUTF);
        const f32x4* src = (const f32x4*)out_lds;
        for (int i = tid; i < BM*OUTF/4; i += 512)
            __builtin_nontemporal_store(src[i], &dst[i]);
    };

    int p = 0;
    for (int t = 0; t < SEQ; ++t) {
        if (t > 0) copy_out(t-1);                 // reads out_lds(t-1)
        const unsigned short* Wf = t ? Wc : Wi;   // t=0: x0 @ W_ih.T (h0=0)
        gepass(0, Wf, p);                         // h_new[0:128]   -> hbuf[p^1]
        gepass(1, Wf, p);                         // h_new[128:256] -> hbuf[p^1]
        SBAR();   // h_new visible; copy_out LDS reads drained
        oproj(p^1);                               // out(t) = f(h_new) -> out_lds
        p ^= 1;
        SBAR();   // out_lds(t) visible; oproj's hbuf reads drained
    }
    copy_out(SEQ-1);
}

extern "C" void kernel_launch(void* const* d_in, const int* in_sizes, int n_in,
                              void* d_out, int out_size, void* d_ws, size_t ws_size,
                              hipStream_t stream) {
    const float* noise   = (const float*)d_in[0];
    const float* W_proj  = (const float*)d_in[1];
    const float* b_proj  = (const float*)d_in[2];
    const float* W_ih    = (const float*)d_in[3];
    const float* W_hh    = (const float*)d_in[4];
    const float* b_ih    = (const float*)d_in[5];
    const float* b_hh    = (const float*)d_in[6];
    const float* W_tech  = (const float*)d_in[7];
    const float* b_tech  = (const float*)d_in[8];
    const float* W_phase = (const float*)d_in[9];
    const float* b_phase = (const float*)d_in[10];
    const float* W_time  = (const float*)d_in[11];
    const float* b_time  = (const float*)d_in[12];

    char* ws = (char*)d_ws;
    unsigned short* Wc = (unsigned short*)(ws);            // 512 KiB: frag(W_ih + W_hh)
    unsigned short* Wi = (unsigned short*)(ws + 524288);   // 512 KiB: frag(W_ih)
    unsigned short* Wo = (unsigned short*)(ws + 1048576);  // 112 KiB: frag(W_out padded to 224)
    unsigned short* Wp = (unsigned short*)(ws + 1163264);  //  64 KiB: frag(W_proj padded K=128)
    float* b_comb = (float*)(ws + 1228800);                //   4 KiB
    float* b_out  = (float*)(ws + 1232896);                // 896 B

    prep_kernel<<<1024, 256, 0, stream>>>(W_proj, W_ih, W_hh, b_ih, b_hh,
                                          W_tech, b_tech, W_phase, b_phase, W_time, b_time,
                                          Wc, Wi, Wo, Wp, b_comb, b_out);
    lstm_kernel<<<NBLK, 512, 0, stream>>>(noise, b_proj, Wc, Wi, Wo, Wp, b_comb, b_out,
                                          (float*)d_out);
}